// Round 1
// baseline (249.651 us; speedup 1.0000x reference)
//
#include <hip/hip_runtime.h>
#include <hip/hip_bf16.h>
#include <stdint.h>

#define NTOK 2048
#define NE 64
#define TOPK 4
#define DM 512
#define DF 2048
#define TOTSLOT (NTOK*TOPK)   // 8192

// GEMM tile config: one 192-row M-tile per expert covers counts up to 192
// (mean 128, sigma ~11). Worst case handled by MT_MAX tiles w/ early exit.
#define BM 192
#define BN 128
#define BK 64
#define MT_MAX 11             // ceil(2048/192)

typedef __bf16 bf16;
typedef __bf16 bf16x8 __attribute__((ext_vector_type(8)));
typedef __bf16 bf16x4 __attribute__((ext_vector_type(4)));
typedef float  f32x4  __attribute__((ext_vector_type(4)));
typedef short  short8 __attribute__((ext_vector_type(8)));

// ---------------- routing ----------------

__global__ void k_init(int* counts, int* fill) {
  int i = threadIdx.x;
  if (i < NE) { counts[i] = 0; fill[i] = 0; }
}

__global__ void k_route(const float* __restrict__ hw, float* __restrict__ top_w,
                        int* __restrict__ top_idx, int* __restrict__ counts) {
  int t = blockIdx.x * blockDim.x + threadIdx.x;
  if (t >= NTOK) return;
  const float* r = hw + (size_t)t * NE;
  float v[TOPK]; int id[TOPK];
  #pragma unroll
  for (int k = 0; k < TOPK; ++k) {
    float best = -1e30f; int bi = 0;
    for (int e = 0; e < NE; ++e) {
      float x = r[e];
      bool used = false;
      for (int j = 0; j < k; ++j) used |= (id[j] == e);
      if (!used && x > best) { best = x; bi = e; }
    }
    v[k] = best; id[k] = bi;
  }
  float den = v[0] + v[1] + v[2] + v[3] + 1e-8f;   // matches ref: sum + 1e-8
  #pragma unroll
  for (int k = 0; k < TOPK; ++k) {
    top_w[t*TOPK + k] = v[k] / den;
    top_idx[t*TOPK + k] = id[k];
    atomicAdd(&counts[id[k]], 1);
  }
}

__global__ void k_scan(const int* __restrict__ counts, int* __restrict__ offsets) {
  if (threadIdx.x == 0) {
    int acc = 0;
    for (int e = 0; e < NE; ++e) { offsets[e] = acc; acc += counts[e]; }
    offsets[NE] = acc;   // == 8192
  }
}

__global__ void k_fill(const int* __restrict__ top_idx, const int* __restrict__ offsets,
                       int* __restrict__ fill, int* __restrict__ tok,
                       int* __restrict__ slot_of) {
  int t = blockIdx.x * blockDim.x + threadIdx.x;
  if (t >= NTOK) return;
  #pragma unroll
  for (int k = 0; k < TOPK; ++k) {
    int e = top_idx[t*TOPK + k];
    int pos = offsets[e] + atomicAdd(&fill[e], 1);
    tok[pos] = t;
    slot_of[t*TOPK + k] = pos;
  }
}

__global__ void k_xcast(const float* __restrict__ x, bf16* __restrict__ xb) {
  int i = blockIdx.x * blockDim.x + threadIdx.x;   // one float4 per thread
  int base = i * 4;
  if (base >= NTOK * DM) return;
  float4 f = *(const float4*)(x + base);
  bf16x4 o;
  o[0] = (bf16)f.x; o[1] = (bf16)f.y; o[2] = (bf16)f.z; o[3] = (bf16)f.w;
  *(bf16x4*)(xb + base) = o;
}

// ---------------- grouped GEMM ----------------
// PASS 1: A = gathered x_bf16 rows (CSR), B^T = W_in[e] (F x D fp32), K=DM,
//         epilogue silu(acc+bias_in) -> H bf16
// PASS 2: A = H rows (contiguous slots), B^T = W_out[e] (D x F fp32), K=DF,
//         epilogue acc+bias_out -> O fp32 (per-slot)
// LDS layout: [row][64 cols] bf16 with 16B-unit XOR swizzle (unit ^= row&7)
// to kill the 16-way bank conflict of 128B-stride rows on ds_read_b128.

template<int PASS>
__global__ __launch_bounds__(512) void k_gemm(
    const float* __restrict__ W, const float* __restrict__ bias,
    const bf16* __restrict__ Asrc, const int* __restrict__ tok,
    const int* __restrict__ offsets,
    bf16* __restrict__ Hout, float* __restrict__ Oout)
{
  constexpr int K    = (PASS == 1) ? DM : DF;
  constexpr int NDIM = (PASS == 1) ? DF : DM;
  constexpr int KT   = K / BK;
  constexpr int NOUT = NDIM;   // stride of output row

  const int e     = blockIdx.z;
  const int mtile = blockIdx.y;
  const int ntile = blockIdx.x;
  const int off   = offsets[e];
  const int cnt   = offsets[e+1] - off;
  if (mtile * BM >= cnt) return;            // early-exit: uniform per block
  const int rowcount = cnt - mtile * BM;    // may exceed BM; only r<rowcount valid
  const int tid = threadIdx.x;

  __shared__ bf16 As[BM * BK];   // 24 KB
  __shared__ bf16 Bs[BN * BK];   // 16 KB

  // --- A staging map: 3 chunks x (512 thr x 8 bf16) covers 192x64 ---
  const bf16* abase[3]; bool aok[3];
  #pragma unroll
  for (int c = 0; c < 3; ++c) {
    int r = (c * 512 + tid) >> 3;           // row in tile 0..191
    aok[c] = (r < rowcount);
    int srcrow;
    if (PASS == 1) srcrow = aok[c] ? tok[off + mtile*BM + r] : 0;
    else           srcrow = min(off + mtile*BM + r, TOTSLOT - 1);
    abase[c] = Asrc + (size_t)srcrow * K + (tid & 7) * 8;
  }
  // --- B staging map: thread -> (row = tid>>2, 16-col segment) ---
  const int brow = tid >> 2;
  const int bcolseg = (tid & 3) * 16;
  const float* bbase = W + (size_t)e * NDIM * K + (size_t)(ntile*BN + brow) * K + bcolseg;

  // --- wave / fragment geometry: 8 waves = 4(M) x 2(N), wave tile 48x64 ---
  const int wave = tid >> 6, lane = tid & 63;
  const int wm = wave >> 1, wn = wave & 1;
  const int lrow = lane >> 4, lcol = lane & 15;

  f32x4 acc[3][4];
  #pragma unroll
  for (int i = 0; i < 3; ++i)
    #pragma unroll
    for (int j = 0; j < 4; ++j) acc[i][j] = (f32x4)(0.0f);

  #pragma unroll 1
  for (int kt = 0; kt < KT; ++kt) {
    const int k0 = kt * BK;
    // load A (bf16, 16B/lane) and B (fp32, 4x float4/lane) to regs
    short8 areg[3];
    #pragma unroll
    for (int c = 0; c < 3; ++c) {
      if (PASS == 2 || aok[c]) areg[c] = *(const short8*)(abase[c] + k0);
      else                     areg[c] = (short8){0,0,0,0,0,0,0,0};
    }
    float4 breg[4];
    #pragma unroll
    for (int q = 0; q < 4; ++q) breg[q] = *(const float4*)(bbase + k0 + q*4);

    __syncthreads();   // previous tile fully consumed
    // write A (swizzled 16B units)
    #pragma unroll
    for (int c = 0; c < 3; ++c) {
      int r = (c * 512 + tid) >> 3;
      int u = tid & 7;
      *(short8*)(&As[r*BK + ((u ^ (r & 7)) * 8)]) = areg[c];
    }
    // convert + write B (fp32 -> bf16, two swizzled 16B units)
    {
      const float* fv = (const float*)breg;
      bf16x8 p0, p1;
      #pragma unroll
      for (int q = 0; q < 8; ++q) { p0[q] = (bf16)fv[q]; p1[q] = (bf16)fv[q+8]; }
      int u0 = (tid & 3) * 2;
      *(bf16x8*)(&Bs[brow*BK + (((u0  ) ^ (brow & 7)) * 8)]) = p0;
      *(bf16x8*)(&Bs[brow*BK + (((u0+1) ^ (brow & 7)) * 8)]) = p1;
    }
    __syncthreads();   // staging visible (barrier drains vmcnt+lgkmcnt)

    // compute: 2 MFMA K-subtiles of 32
    #pragma unroll
    for (int ks = 0; ks < 2; ++ks) {
      const int uu = ks*4 + lrow;           // 16B unit within row
      bf16x8 af[3], bfr[4];
      #pragma unroll
      for (int i = 0; i < 3; ++i) {
        int m = wm*48 + i*16 + lcol;
        af[i] = *(const bf16x8*)(&As[m*BK + ((uu ^ (m & 7)) * 8)]);
      }
      #pragma unroll
      for (int j = 0; j < 4; ++j) {
        int n = wn*64 + j*16 + lcol;
        bfr[j] = *(const bf16x8*)(&Bs[n*BK + ((uu ^ (n & 7)) * 8)]);
      }
      #pragma unroll
      for (int i = 0; i < 3; ++i)
        #pragma unroll
        for (int j = 0; j < 4; ++j)
          acc[i][j] = __builtin_amdgcn_mfma_f32_16x16x32_bf16(af[i], bfr[j], acc[i][j], 0, 0, 0);
    }
  }

  // --- epilogue. C/D layout: col = lane&15, row = (lane>>4)*4 + reg ---
  const int slotbase = off + mtile * BM;
  #pragma unroll
  for (int i = 0; i < 3; ++i) {
    const int rbase = wm*48 + i*16 + lrow*4;
    #pragma unroll
    for (int j = 0; j < 4; ++j) {
      const int gcol = ntile*BN + wn*64 + j*16 + lcol;
      const float bv = bias[(size_t)e * NOUT + gcol];
      #pragma unroll
      for (int q = 0; q < 4; ++q) {
        const int r = rbase + q;
        if (r < rowcount) {
          float h = acc[i][j][q] + bv;
          if (PASS == 1) {
            float s = h / (1.0f + __expf(-h));      // silu
            Hout[(size_t)(slotbase + r) * DF + gcol] = (bf16)s;
          } else {
            Oout[(size_t)(slotbase + r) * DM + gcol] = h;
          }
        }
      }
    }
  }
}

// ---------------- combine (deterministic, atomic-free) ----------------

__global__ void k_combine(const float* __restrict__ O, const float* __restrict__ top_w,
                          const int* __restrict__ slot_of, float* __restrict__ out) {
  int i = blockIdx.x * blockDim.x + threadIdx.x;   // one float4 per thread
  if (i >= NTOK * DM / 4) return;
  int t  = i / (DM / 4);
  int d4 = (i % (DM / 4)) * 4;
  float4 s = {0.f, 0.f, 0.f, 0.f};
  #pragma unroll
  for (int k = 0; k < TOPK; ++k) {
    float w = top_w[t*TOPK + k];
    int  sl = slot_of[t*TOPK + k];
    float4 o = *(const float4*)(O + (size_t)sl * DM + d4);
    s.x += w * o.x; s.y += w * o.y; s.z += w * o.z; s.w += w * o.w;
  }
  *(float4*)(out + (size_t)t * DM + d4) = s;
}

// ---------------- launch ----------------

extern "C" void kernel_launch(void* const* d_in, const int* in_sizes, int n_in,
                              void* d_out, int out_size, void* d_ws, size_t ws_size,
                              hipStream_t stream) {
  const float* x        = (const float*)d_in[0];
  const float* hw       = (const float*)d_in[1];
  const float* W_in     = (const float*)d_in[2];
  const float* bias_in  = (const float*)d_in[3];
  const float* W_out    = (const float*)d_in[4];
  const float* bias_out = (const float*)d_in[5];
  float* out = (float*)d_out;

  char* ws = (char*)d_ws;
  // ws layout (256B-aligned segments), total ~50.2 MB
  int*   counts  = (int*)  (ws + 0);
  int*   fill    = (int*)  (ws + 1024);
  int*   offsets = (int*)  (ws + 2048);                  // 65 ints
  int*   top_idx = (int*)  (ws + 4096);                  // 32 KB
  float* top_w   = (float*)(ws + 4096 + 32768);          // 32 KB
  int*   slot_of = (int*)  (ws + 4096 + 2*32768);        // 32 KB
  int*   tok     = (int*)  (ws + 4096 + 3*32768);        // 32 KB
  bf16*  xb      = (bf16*) (ws + 4096 + 4*32768);        // 2 MB
  size_t o_xb_end = 4096 + 4*32768 + (size_t)NTOK*DM*2;
  bf16*  H       = (bf16*) (ws + o_xb_end);              // 32 MB
  size_t o_H_end  = o_xb_end + (size_t)TOTSLOT*DF*2;
  float* O       = (float*)(ws + o_H_end);               // 16 MB

  k_init  <<<1, 64, 0, stream>>>(counts, fill);
  k_route <<<NTOK/256, 256, 0, stream>>>(hw, top_w, top_idx, counts);
  k_scan  <<<1, 64, 0, stream>>>(counts, offsets);
  k_fill  <<<NTOK/256, 256, 0, stream>>>(top_idx, offsets, fill, tok, slot_of);
  k_xcast <<<(NTOK*DM/4)/256, 256, 0, stream>>>(x, xb);

  dim3 g1(DF/BN, MT_MAX, NE);   // (16, 11, 64)
  k_gemm<1><<<g1, 512, 0, stream>>>(W_in, bias_in, xb, tok, offsets, H, nullptr);
  dim3 g2(DM/BN, MT_MAX, NE);   // (4, 11, 64)
  k_gemm<2><<<g2, 512, 0, stream>>>(W_out, bias_out, H, nullptr, offsets, nullptr, O);

  k_combine<<<(NTOK*DM/4)/256, 256, 0, stream>>>(O, top_w, slot_of, out);
}